// Round 1
// baseline (319.032 us; speedup 1.0000x reference)
//
#include <hip/hip_runtime.h>

#define NROWS 16384
#define DIM   768
#define PP    256
#define BT    64
#define EPSF  1e-6f

// ---------------------------------------------------------------- kernel 1
// Per-row: inverse L2 norms of input & target, and patch_loss = mean((in-tg)^2).
// One wave (64 lanes) per row, 4 rows per 256-thread workgroup.
__global__ __launch_bounds__(256) void k_norms(const float* __restrict__ in,
                                               const float* __restrict__ tg,
                                               float* __restrict__ inv_in,
                                               float* __restrict__ inv_tg,
                                               float* __restrict__ ploss) {
    int row  = blockIdx.x * 4 + (threadIdx.x >> 6);
    int lane = threadIdx.x & 63;
    const float4* ip = (const float4*)(in + (size_t)row * DIM);
    const float4* tp = (const float4*)(tg + (size_t)row * DIM);
    float si = 0.f, st = 0.f, sd = 0.f;
    for (int v = lane; v < DIM / 4; v += 64) {
        float4 a = ip[v], b = tp[v];
        si += a.x * a.x + a.y * a.y + a.z * a.z + a.w * a.w;
        st += b.x * b.x + b.y * b.y + b.z * b.z + b.w * b.w;
        float dx = a.x - b.x, dy = a.y - b.y, dz = a.z - b.z, dw = a.w - b.w;
        sd += dx * dx + dy * dy + dz * dz + dw * dw;
    }
#pragma unroll
    for (int o = 32; o; o >>= 1) {
        si += __shfl_down(si, o);
        st += __shfl_down(st, o);
        sd += __shfl_down(sd, o);
    }
    if (lane == 0) {
        inv_in[row] = 1.f / fmaxf(sqrtf(si), 1e-12f);
        inv_tg[row] = 1.f / fmaxf(sqrtf(st), 1e-12f);
        ploss[row]  = sd * (1.f / DIM);
    }
}

// ---------------------------------------------------------------- kernel 2
// Per-(bt-block, d): sum over the 256 rows of normalized target -> bsum[b][d].
__global__ __launch_bounds__(128) void k_blocksum(const float* __restrict__ tg,
                                                  const float* __restrict__ inv_tg,
                                                  float* __restrict__ bsum) {
    int b = blockIdx.x;
    int d = blockIdx.y * 128 + threadIdx.x;
    float s = 0.f;
    size_t base = (size_t)b * PP * DIM + d;
    for (int r = 0; r < PP; ++r)
        s += tg[base + (size_t)r * DIM] * inv_tg[b * PP + r];
    bsum[b * DIM + d] = s;
}

// ---------------------------------------------------------------- kernel 3
// Per bt-block (one WG of 256 threads, thread p owns row p):
//   tf  = 1/(tg_n[p] . blockmean + eps)
//   idf = 1/(tg_n[p] . globalmean + eps)
//   w   = tf*idf, normalized by block sum; store weights; accumulate sim-loss.
__global__ __launch_bounds__(256) void k_weights(const float* __restrict__ tg,
                                                 const float* __restrict__ inv_tg,
                                                 const float* __restrict__ bsum,
                                                 const float* __restrict__ ploss,
                                                 float* __restrict__ weights,
                                                 float* __restrict__ accum) {
    __shared__ __align__(16) float vb[DIM];
    __shared__ __align__(16) float va[DIM];
    __shared__ float red[256];
    int b = blockIdx.x, p = threadIdx.x;
    int row = b * PP + p;
    for (int d = p; d < DIM; d += 256) {
        float all = 0.f;
        for (int bb = 0; bb < BT; ++bb) all += bsum[bb * DIM + d];
        va[d] = all * (1.f / NROWS);   // global mean of tg_n
        vb[d] = bsum[b * DIM + d] * (1.f / PP);  // block mean of tg_n
    }
    __syncthreads();
    const float4* tp  = (const float4*)(tg + (size_t)row * DIM);
    const float4* vb4 = (const float4*)vb;
    const float4* va4 = (const float4*)va;
    float itg = inv_tg[row];
    float db = 0.f, da = 0.f;
    for (int v = 0; v < DIM / 4; ++v) {
        float4 t = tp[v], x = vb4[v], y = va4[v];
        db += t.x * x.x + t.y * x.y + t.z * x.z + t.w * x.w;
        da += t.x * y.x + t.y * y.y + t.z * y.z + t.w * y.w;
    }
    db *= itg; da *= itg;
    float w = (1.f / (db + EPSF)) * (1.f / (da + EPSF));
    red[p] = w; __syncthreads();
    for (int s = 128; s; s >>= 1) { if (p < s) red[p] += red[p + s]; __syncthreads(); }
    float wn = w / (red[0] + EPSF);
    weights[row] = wn;
    __syncthreads();  // protect red[] before reuse
    red[p] = wn * ploss[row]; __syncthreads();
    for (int s = 128; s; s >>= 1) { if (p < s) red[p] += red[p + s]; __syncthreads(); }
    if (p == 0) atomicAdd(&accum[0], red[0]);
}

// ---------------------------------------------------------------- kernel 4
// Gram loss. Each WG: one 128x128 tile of one block's 256x256 gram pair.
// K-chunk = 16 staged in LDS (k-major, pitch 132: conflict-free stores,
// 16B-aligned contiguous 8-float fragments for b128 reads).
// Thread (ty,tx) of 16x16 computes an 8x8 micro-tile of BOTH grams, then the
// weighted squared diff, block-reduce, one atomicAdd per WG.
#define KC    16
#define PITCH 132
__global__ __launch_bounds__(256) void k_gram(const float* __restrict__ in,
                                              const float* __restrict__ tg,
                                              const float* __restrict__ inv_in,
                                              const float* __restrict__ inv_tg,
                                              const float* __restrict__ weights,
                                              float* __restrict__ gacc) {
    __shared__ float Ain[KC][PITCH];
    __shared__ float Atg[KC][PITCH];
    __shared__ float Bin[KC][PITCH];
    __shared__ float Btg[KC][PITCH];
    __shared__ float red[256];
    int wg = blockIdx.x;
    int b = wg >> 2, t = wg & 3;
    int pr = (t >> 1) * 128, qc = (t & 1) * 128;
    int tid = threadIdx.x;
    int ty = tid >> 4, tx = tid & 15;
    int klane = tid & 15, r0 = tid >> 4;  // loader: fixed k column, rows r0+16i

    float accA[8][8], accB[8][8];
#pragma unroll
    for (int i = 0; i < 8; ++i)
#pragma unroll
        for (int j = 0; j < 8; ++j) { accA[i][j] = 0.f; accB[i][j] = 0.f; }

    const size_t rowbase = (size_t)b * PP * DIM;
    const int bP = b * PP;

    // hoist normalization scales (constant across k0)
    float sA[8], sAt[8], sB[8], sBt[8];
#pragma unroll
    for (int i = 0; i < 8; ++i) {
        int rp = pr + r0 + 16 * i, rq = qc + r0 + 16 * i;
        sA[i]  = inv_in[bP + rp];
        sAt[i] = inv_tg[bP + rp];
        sB[i]  = inv_in[bP + rq];
        sBt[i] = inv_tg[bP + rq];
    }

    for (int k0 = 0; k0 < DIM; k0 += KC) {
#pragma unroll
        for (int i = 0; i < 8; ++i) {
            int r = r0 + 16 * i;
            size_t offP = rowbase + (size_t)(pr + r) * DIM + k0 + klane;
            size_t offQ = rowbase + (size_t)(qc + r) * DIM + k0 + klane;
            Ain[klane][r] = in[offP] * sA[i];
            Atg[klane][r] = tg[offP] * sAt[i];
            Bin[klane][r] = in[offQ] * sB[i];
            Btg[klane][r] = tg[offQ] * sBt[i];
        }
        __syncthreads();
#pragma unroll
        for (int kk = 0; kk < KC; ++kk) {
            float a0[8], a1[8], b0[8], b1[8];
#pragma unroll
            for (int i = 0; i < 8; ++i) { a0[i] = Ain[kk][ty * 8 + i]; a1[i] = Atg[kk][ty * 8 + i]; }
#pragma unroll
            for (int j = 0; j < 8; ++j) { b0[j] = Bin[kk][tx * 8 + j]; b1[j] = Btg[kk][tx * 8 + j]; }
#pragma unroll
            for (int i = 0; i < 8; ++i)
#pragma unroll
                for (int j = 0; j < 8; ++j) {
                    accA[i][j] += a0[i] * b0[j];
                    accB[i][j] += a1[i] * b1[j];
                }
        }
        __syncthreads();
    }

    // epilogue: weighted squared diff
    float local = 0.f;
#pragma unroll
    for (int i = 0; i < 8; ++i) {
        float wp = weights[bP + pr + ty * 8 + i];
#pragma unroll
        for (int j = 0; j < 8; ++j) {
            float wq = weights[bP + qc + tx * 8 + j];
            float df = accA[i][j] - accB[i][j];
            local += wp * wq * df * df;
        }
    }
    red[tid] = local; __syncthreads();
    for (int s = 128; s; s >>= 1) { if (tid < s) red[tid] += red[tid + s]; __syncthreads(); }
    if (tid == 0) atomicAdd(gacc, red[0]);
}

// ---------------------------------------------------------------- kernel 5
__global__ void k_final(const float* __restrict__ accum, float* __restrict__ out) {
    out[0] = (accum[0] + 10.f * accum[1]) * (1.f / BT);
}

// ---------------------------------------------------------------- launch
extern "C" void kernel_launch(void* const* d_in, const int* in_sizes, int n_in,
                              void* d_out, int out_size, void* d_ws, size_t ws_size,
                              hipStream_t stream) {
    (void)in_sizes; (void)n_in; (void)out_size; (void)ws_size;
    const float* in = (const float*)d_in[0];
    const float* tg = (const float*)d_in[1];
    float* ws      = (float*)d_ws;
    float* inv_in  = ws;
    float* inv_tg  = ws + NROWS;
    float* ploss   = ws + 2 * NROWS;
    float* weights = ws + 3 * NROWS;
    float* bsum    = ws + 4 * NROWS;             // BT*DIM floats
    float* accum   = ws + 4 * NROWS + BT * DIM;  // [0]=sim, [1]=gram

    hipMemsetAsync(accum, 0, 2 * sizeof(float), stream);
    k_norms<<<NROWS / 4, 256, 0, stream>>>(in, tg, inv_in, inv_tg, ploss);
    k_blocksum<<<dim3(BT, DIM / 128), 128, 0, stream>>>(tg, inv_tg, bsum);
    k_weights<<<BT, 256, 0, stream>>>(tg, inv_tg, bsum, ploss, weights, accum);
    k_gram<<<BT * 4, 256, 0, stream>>>(in, tg, inv_in, inv_tg, weights, accum + 1);
    k_final<<<1, 1, 0, stream>>>(accum, (float*)d_out);
}

// Round 2
// 108.936 us; speedup vs baseline: 2.9286x; 2.9286x over previous
//
#include <hip/hip_runtime.h>
#include <hip/hip_bf16.h>

#define NROWS 16384
#define DIM   768
#define PP    256
#define BT    64
#define EPSF  1e-6f
#define KC    32
#define LP    40   // LDS row pitch in ushorts (80 B)

typedef short          bf16x8 __attribute__((ext_vector_type(8)));
typedef float          f32x4  __attribute__((ext_vector_type(4)));
typedef unsigned short us4    __attribute__((ext_vector_type(4)));
typedef unsigned short us8    __attribute__((ext_vector_type(8)));

__device__ __forceinline__ unsigned short f2bf(float x) {
    __hip_bfloat16 h = __float2bfloat16(x);
    return *reinterpret_cast<unsigned short*>(&h);
}

// ---------------------------------------------------------------- kernel 1
// Per-row inv-norms + patch_loss; optionally writes bf16 normalized rows.
template<int PRE>
__global__ __launch_bounds__(256) void k_norms(const float* __restrict__ in,
                                               const float* __restrict__ tg,
                                               float* __restrict__ inv_in,
                                               float* __restrict__ inv_tg,
                                               float* __restrict__ ploss,
                                               unsigned short* __restrict__ in_n,
                                               unsigned short* __restrict__ tg_n) {
    int row  = blockIdx.x * 4 + (threadIdx.x >> 6);
    int lane = threadIdx.x & 63;
    const float4* ip = (const float4*)(in + (size_t)row * DIM);
    const float4* tp = (const float4*)(tg + (size_t)row * DIM);
    float4 a[3], t[3];
#pragma unroll
    for (int v = 0; v < 3; ++v) { a[v] = ip[lane + 64 * v]; t[v] = tp[lane + 64 * v]; }
    float si = 0.f, st = 0.f, sd = 0.f;
#pragma unroll
    for (int v = 0; v < 3; ++v) {
        si += a[v].x * a[v].x + a[v].y * a[v].y + a[v].z * a[v].z + a[v].w * a[v].w;
        st += t[v].x * t[v].x + t[v].y * t[v].y + t[v].z * t[v].z + t[v].w * t[v].w;
        float dx = a[v].x - t[v].x, dy = a[v].y - t[v].y;
        float dz = a[v].z - t[v].z, dw = a[v].w - t[v].w;
        sd += dx * dx + dy * dy + dz * dz + dw * dw;
    }
#pragma unroll
    for (int o = 32; o; o >>= 1) {
        si += __shfl_xor(si, o); st += __shfl_xor(st, o); sd += __shfl_xor(sd, o);
    }
    float ii = 1.f / fmaxf(sqrtf(si), 1e-12f);
    float it = 1.f / fmaxf(sqrtf(st), 1e-12f);
    if (lane == 0) { inv_in[row] = ii; inv_tg[row] = it; ploss[row] = sd * (1.f / DIM); }
    if constexpr (PRE != 0) {
        us4* on = (us4*)(in_n + (size_t)row * DIM);
        us4* ot = (us4*)(tg_n + (size_t)row * DIM);
#pragma unroll
        for (int v = 0; v < 3; ++v) {
            us4 ua, ut;
            ua[0] = f2bf(a[v].x * ii); ua[1] = f2bf(a[v].y * ii);
            ua[2] = f2bf(a[v].z * ii); ua[3] = f2bf(a[v].w * ii);
            ut[0] = f2bf(t[v].x * it); ut[1] = f2bf(t[v].y * it);
            ut[2] = f2bf(t[v].z * it); ut[3] = f2bf(t[v].w * it);
            on[lane + 64 * v] = ua; ot[lane + 64 * v] = ut;
        }
    }
}

// ---------------------------------------------------------------- kernel 2
__global__ __launch_bounds__(128) void k_blocksum(const float* __restrict__ tg,
                                                  const float* __restrict__ inv_tg,
                                                  float* __restrict__ bsum) {
    int b = blockIdx.x;
    int d = blockIdx.y * 128 + threadIdx.x;
    float s = 0.f;
    size_t base = (size_t)b * PP * DIM + d;
    for (int r = 0; r < PP; ++r)
        s += tg[base + (size_t)r * DIM] * inv_tg[b * PP + r];
    bsum[b * DIM + d] = s;
}

// ---------------------------------------------------------------- kernel 3
__global__ __launch_bounds__(256) void k_weights(const float* __restrict__ tg,
                                                 const float* __restrict__ inv_tg,
                                                 const float* __restrict__ bsum,
                                                 const float* __restrict__ ploss,
                                                 float* __restrict__ weights,
                                                 float* __restrict__ accum) {
    __shared__ __align__(16) float vb[DIM];
    __shared__ __align__(16) float va[DIM];
    __shared__ float red[256];
    int b = blockIdx.x, p = threadIdx.x;
    int row = b * PP + p;
    for (int d = p; d < DIM; d += 256) {
        float all = 0.f;
        for (int bb = 0; bb < BT; ++bb) all += bsum[bb * DIM + d];
        va[d] = all * (1.f / NROWS);
        vb[d] = bsum[b * DIM + d] * (1.f / PP);
    }
    __syncthreads();
    const float4* tp  = (const float4*)(tg + (size_t)row * DIM);
    const float4* vb4 = (const float4*)vb;
    const float4* va4 = (const float4*)va;
    float itg = inv_tg[row];
    float db = 0.f, da = 0.f;
    for (int v = 0; v < DIM / 4; ++v) {
        float4 t = tp[v], x = vb4[v], y = va4[v];
        db += t.x * x.x + t.y * x.y + t.z * x.z + t.w * x.w;
        da += t.x * y.x + t.y * y.y + t.z * y.z + t.w * y.w;
    }
    db *= itg; da *= itg;
    float w = (1.f / (db + EPSF)) * (1.f / (da + EPSF));
    red[p] = w; __syncthreads();
    for (int s = 128; s; s >>= 1) { if (p < s) red[p] += red[p + s]; __syncthreads(); }
    float wn = w / (red[0] + EPSF);
    weights[row] = wn;
    __syncthreads();
    red[p] = wn * ploss[row]; __syncthreads();
    for (int s = 128; s; s >>= 1) { if (p < s) red[p] += red[p + s]; __syncthreads(); }
    if (p == 0) atomicAdd(&accum[0], red[0]);
}

// ---------------------------------------------------------------- kernel 4
// bf16 MFMA dual-gram. 192 WGs = 64 blocks x 3 tiles (diag0, offdiag x2, diag1).
// WG = 4 waves, each 64x64 of both grams via mfma_f32_16x16x32_bf16.
template<int PRE>
__global__ __launch_bounds__(256) void k_gram(const float* __restrict__ in,
                                              const float* __restrict__ tg,
                                              const unsigned short* __restrict__ in_n,
                                              const unsigned short* __restrict__ tg_n,
                                              const float* __restrict__ inv_in,
                                              const float* __restrict__ inv_tg,
                                              const float* __restrict__ weights,
                                              float* __restrict__ gacc) {
    __shared__ __align__(16) unsigned short LA0[128 * LP];
    __shared__ __align__(16) unsigned short LA1[128 * LP];
    __shared__ __align__(16) unsigned short LB0[128 * LP];
    __shared__ __align__(16) unsigned short LB1[128 * LP];
    __shared__ float red[256];

    const int wg  = blockIdx.x;
    const int xcd = wg & 7, j = wg >> 3;          // XCD-chunked: 8 blocks per XCD
    const int b   = xcd * 8 + j / 3;
    const int t3  = j % 3;
    const int pr  = (t3 == 2) ? 128 : 0;
    const int qc  = (t3 == 0) ? 0 : 128;
    const bool diag = (pr == qc);
    const float factor = diag ? 1.f : 2.f;

    const int tid  = threadIdx.x;
    const int lane = tid & 63;
    const int wave = tid >> 6;
    const int wr = (wave >> 1) * 64, wc = (wave & 1) * 64;
    const int bP = b * PP;

    // staging role: 4 lanes per row, thread covers rows strow and strow+64
    const int strow = tid >> 2;
    const int skq   = tid & 3;            // 8-elem chunk within KC=32
    const int sw    = (strow >> 3) & 3;   // bank swizzle (same for both h)

    const float* srcf[4] = { in, tg, in, tg };
    const unsigned short* srcn[4] = { in_n, tg_n, in_n, tg_n };
    unsigned short* ldst[4] = { LA0, LA1, LB0, LB1 };

    size_t g[4][2];
#pragma unroll
    for (int h = 0; h < 2; ++h) {
        g[0][h] = (size_t)(bP + pr + strow + h * 64) * DIM + skq * 8;
        g[1][h] = g[0][h];
        g[2][h] = (size_t)(bP + qc + strow + h * 64) * DIM + skq * 8;
        g[3][h] = g[2][h];
    }
    float scl[4][2];
    if constexpr (PRE == 0) {
#pragma unroll
        for (int h = 0; h < 2; ++h) {
            scl[0][h] = inv_in[bP + pr + strow + h * 64];
            scl[1][h] = inv_tg[bP + pr + strow + h * 64];
            scl[2][h] = inv_in[bP + qc + strow + h * 64];
            scl[3][h] = inv_tg[bP + qc + strow + h * 64];
        }
    }

    float4 pfa[4][2], pfb[4][2];  // PRE=0 staging regs
    us8    pn[4][2];              // PRE=1 staging regs

    auto STAGE_LOAD = [&](int k0) {
#pragma unroll
        for (int bi = 0; bi < 4; ++bi) {
            if (bi >= 2 && diag) continue;
#pragma unroll
            for (int h = 0; h < 2; ++h) {
                if constexpr (PRE != 0) {
                    pn[bi][h] = *(const us8*)(srcn[bi] + g[bi][h] + k0);
                } else {
                    pfa[bi][h] = *(const float4*)(srcf[bi] + g[bi][h] + k0);
                    pfb[bi][h] = *(const float4*)(srcf[bi] + g[bi][h] + k0 + 4);
                }
            }
        }
    };
    auto STAGE_WRITE = [&]() {
#pragma unroll
        for (int bi = 0; bi < 4; ++bi) {
            if (bi >= 2 && diag) continue;
#pragma unroll
            for (int h = 0; h < 2; ++h) {
                us8 v;
                if constexpr (PRE != 0) {
                    v = pn[bi][h];
                } else {
                    float s = scl[bi][h];
                    float4 x = pfa[bi][h], y = pfb[bi][h];
                    v[0] = f2bf(x.x * s); v[1] = f2bf(x.y * s);
                    v[2] = f2bf(x.z * s); v[3] = f2bf(x.w * s);
                    v[4] = f2bf(y.x * s); v[5] = f2bf(y.y * s);
                    v[6] = f2bf(y.z * s); v[7] = f2bf(y.w * s);
                }
                int row = strow + h * 64;
                *(us8*)&ldst[bi][row * LP + (skq ^ sw) * 8] = v;
            }
        }
    };

    const unsigned short* RB0 = diag ? LA0 : LB0;
    const unsigned short* RB1 = diag ? LA1 : LB1;

    f32x4 accI[4][4], accT[4][4];
#pragma unroll
    for (int m = 0; m < 4; ++m)
#pragma unroll
        for (int n = 0; n < 4; ++n) {
            f32x4 z = { 0.f, 0.f, 0.f, 0.f };
            accI[m][n] = z; accT[m][n] = z;
        }

    STAGE_LOAD(0);
    for (int ks = 0; ks < DIM / KC; ++ks) {
        __syncthreads();
        STAGE_WRITE();
        __syncthreads();
        if (ks + 1 < DIM / KC) STAGE_LOAD(KC * (ks + 1));

        bf16x8 aI[4], aT[4], bI[4], bT[4];
#pragma unroll
        for (int m = 0; m < 4; ++m) {
            int row = wr + m * 16 + (lane & 15);
            int off = row * LP + (((lane >> 4) ^ ((row >> 3) & 3))) * 8;
            aI[m] = *(const bf16x8*)&LA0[off];
            aT[m] = *(const bf16x8*)&LA1[off];
        }
#pragma unroll
        for (int n = 0; n < 4; ++n) {
            int row = wc + n * 16 + (lane & 15);
            int off = row * LP + (((lane >> 4) ^ ((row >> 3) & 3))) * 8;
            bI[n] = *(const bf16x8*)&RB0[off];
            bT[n] = *(const bf16x8*)&RB1[off];
        }
#pragma unroll
        for (int m = 0; m < 4; ++m)
#pragma unroll
            for (int n = 0; n < 4; ++n) {
                accI[m][n] = __builtin_amdgcn_mfma_f32_16x16x32_bf16(aI[m], bI[n], accI[m][n], 0, 0, 0);
                accT[m][n] = __builtin_amdgcn_mfma_f32_16x16x32_bf16(aT[m], bT[n], accT[m][n], 0, 0, 0);
            }
    }

    // epilogue: weighted squared diff.  C/D: col=lane&15, row=(lane>>4)*4+r
    const int r4 = lane >> 4, cl = lane & 15;
    float wq[4], wp[4][4];
#pragma unroll
    for (int n = 0; n < 4; ++n) wq[n] = weights[bP + qc + wc + n * 16 + cl];
#pragma unroll
    for (int m = 0; m < 4; ++m)
#pragma unroll
        for (int r = 0; r < 4; ++r) wp[m][r] = weights[bP + pr + wr + m * 16 + r4 * 4 + r];
    float local = 0.f;
#pragma unroll
    for (int m = 0; m < 4; ++m)
#pragma unroll
        for (int n = 0; n < 4; ++n)
#pragma unroll
            for (int r = 0; r < 4; ++r) {
                float d = accI[m][n][r] - accT[m][n][r];
                local += wp[m][r] * wq[n] * d * d;
            }
    local *= factor;
    red[tid] = local; __syncthreads();
    for (int s = 128; s; s >>= 1) { if (tid < s) red[tid] += red[tid + s]; __syncthreads(); }
    if (tid == 0) atomicAdd(gacc, red[0]);
}

// ---------------------------------------------------------------- kernel 5
__global__ void k_final(const float* __restrict__ accum, float* __restrict__ out) {
    out[0] = (accum[0] + 10.f * accum[1]) * (1.f / BT);
}

// ---------------------------------------------------------------- launch
extern "C" void kernel_launch(void* const* d_in, const int* in_sizes, int n_in,
                              void* d_out, int out_size, void* d_ws, size_t ws_size,
                              hipStream_t stream) {
    (void)in_sizes; (void)n_in; (void)out_size;
    const float* in = (const float*)d_in[0];
    const float* tg = (const float*)d_in[1];

    const size_t bfBytes   = (size_t)NROWS * DIM * 2;       // one bf16 matrix
    const size_t floatsOff = 2 * bfBytes;
    const size_t fCount    = 4 * NROWS + BT * DIM + 2;
    const size_t needed    = floatsOff + fCount * 4;
    const bool   pre       = ws_size >= needed;

    char* wsb = (char*)d_ws;
    unsigned short* in_n = nullptr;
    unsigned short* tg_n = nullptr;
    float* fbase;
    if (pre) {
        in_n  = (unsigned short*)wsb;
        tg_n  = (unsigned short*)(wsb + bfBytes);
        fbase = (float*)(wsb + floatsOff);
    } else {
        fbase = (float*)wsb;
    }
    float* inv_in  = fbase;
    float* inv_tg  = fbase + NROWS;
    float* ploss   = fbase + 2 * NROWS;
    float* weights = fbase + 3 * NROWS;
    float* bsum    = fbase + 4 * NROWS;
    float* accum   = fbase + 4 * NROWS + BT * DIM;

    hipMemsetAsync(accum, 0, 2 * sizeof(float), stream);
    if (pre) {
        k_norms<1><<<NROWS / 4, 256, 0, stream>>>(in, tg, inv_in, inv_tg, ploss, in_n, tg_n);
    } else {
        k_norms<0><<<NROWS / 4, 256, 0, stream>>>(in, tg, inv_in, inv_tg, ploss, nullptr, nullptr);
    }
    k_blocksum<<<dim3(BT, DIM / 128), 128, 0, stream>>>(tg, inv_tg, bsum);
    k_weights<<<BT, 256, 0, stream>>>(tg, inv_tg, bsum, ploss, weights, accum);
    if (pre) {
        k_gram<1><<<192, 256, 0, stream>>>(in, tg, in_n, tg_n, inv_in, inv_tg, weights, accum + 1);
    } else {
        k_gram<0><<<192, 256, 0, stream>>>(in, tg, in_n, tg_n, inv_in, inv_tg, weights, accum + 1);
    }
    k_final<<<1, 1, 0, stream>>>(accum, (float*)d_out);
}

// Round 4
// 86.577 us; speedup vs baseline: 3.6850x; 1.2583x over previous
//
#include <hip/hip_runtime.h>
#include <hip/hip_bf16.h>

#define NROWS 16384
#define DIM   768
#define PP    256
#define BT    64
#define EPSF  1e-6f
#define KC    32
#define LP    40   // LDS row pitch in ushorts (80 B)

typedef short          bf16x8 __attribute__((ext_vector_type(8)));
typedef float          f32x4  __attribute__((ext_vector_type(4)));
typedef unsigned short us4    __attribute__((ext_vector_type(4)));
typedef unsigned short us8    __attribute__((ext_vector_type(8)));

__device__ __forceinline__ unsigned short f2bf(float x) {
    __hip_bfloat16 h = __float2bfloat16(x);
    return *reinterpret_cast<unsigned short*>(&h);
}

// ---------------------------------------------------------------- kernel 1
// Per-row inv-norms + patch_loss; optionally writes bf16 normalized rows.
template<int PRE>
__global__ __launch_bounds__(256) void k_norms(const float* __restrict__ in,
                                               const float* __restrict__ tg,
                                               float* __restrict__ inv_in,
                                               float* __restrict__ inv_tg,
                                               float* __restrict__ ploss,
                                               unsigned short* __restrict__ in_n,
                                               unsigned short* __restrict__ tg_n) {
    int row  = blockIdx.x * 4 + (threadIdx.x >> 6);
    int lane = threadIdx.x & 63;
    const float4* ip = (const float4*)(in + (size_t)row * DIM);
    const float4* tp = (const float4*)(tg + (size_t)row * DIM);
    float4 a[3], t[3];
#pragma unroll
    for (int v = 0; v < 3; ++v) { a[v] = ip[lane + 64 * v]; t[v] = tp[lane + 64 * v]; }
    float si = 0.f, st = 0.f, sd = 0.f;
#pragma unroll
    for (int v = 0; v < 3; ++v) {
        si += a[v].x * a[v].x + a[v].y * a[v].y + a[v].z * a[v].z + a[v].w * a[v].w;
        st += t[v].x * t[v].x + t[v].y * t[v].y + t[v].z * t[v].z + t[v].w * t[v].w;
        float dx = a[v].x - t[v].x, dy = a[v].y - t[v].y;
        float dz = a[v].z - t[v].z, dw = a[v].w - t[v].w;
        sd += dx * dx + dy * dy + dz * dz + dw * dw;
    }
#pragma unroll
    for (int o = 32; o; o >>= 1) {
        si += __shfl_xor(si, o); st += __shfl_xor(st, o); sd += __shfl_xor(sd, o);
    }
    float ii = 1.f / fmaxf(sqrtf(si), 1e-12f);
    float it = 1.f / fmaxf(sqrtf(st), 1e-12f);
    if (lane == 0) { inv_in[row] = ii; inv_tg[row] = it; ploss[row] = sd * (1.f / DIM); }
    if constexpr (PRE != 0) {
        us4* on = (us4*)(in_n + (size_t)row * DIM);
        us4* ot = (us4*)(tg_n + (size_t)row * DIM);
#pragma unroll
        for (int v = 0; v < 3; ++v) {
            us4 ua, ut;
            ua[0] = f2bf(a[v].x * ii); ua[1] = f2bf(a[v].y * ii);
            ua[2] = f2bf(a[v].z * ii); ua[3] = f2bf(a[v].w * ii);
            ut[0] = f2bf(t[v].x * it); ut[1] = f2bf(t[v].y * it);
            ut[2] = f2bf(t[v].z * it); ut[3] = f2bf(t[v].w * it);
            on[lane + 64 * v] = ua; ot[lane + 64 * v] = ut;
        }
    }
}

// ------------------------------------------- weights pipeline (all f32!)
// The tf/idf denominators are near-zero means (gram row-mean ~4e-3±2.3e-3,
// cross_mean ~6e-5±2.8e-4) — bf16 inputs flip their signs. Must stay f32.

// stage 1: partial block sums of normalized target rows, rows split in two
// halves for parallelism (deterministic). psum[b][h][d], h in {0,1}.
__global__ __launch_bounds__(64) void k_bsum1(const float* __restrict__ tg,
                                              const float* __restrict__ inv_tg,
                                              float* __restrict__ psum) {
    int b = blockIdx.x, y = blockIdx.y, h = blockIdx.z;
    int d0 = y * 256 + threadIdx.x * 4;
    const float* base = tg + (size_t)b * PP * DIM + (size_t)h * 128 * DIM + d0;
    const float* itg  = inv_tg + b * PP + h * 128;
    float4 s = { 0.f, 0.f, 0.f, 0.f };
    for (int r = 0; r < 128; ++r) {
        float4 v = *(const float4*)(base + (size_t)r * DIM);
        float w = itg[r];
        s.x += v.x * w; s.y += v.y * w; s.z += v.z * w; s.w += v.w * w;
    }
    *(float4*)(psum + (size_t)(b * 2 + h) * DIM + d0) = s;
}

// stage 2: merge halves -> bsum[b][d]; global mean va[d].
__global__ __launch_bounds__(256) void k_bsum2(const float* __restrict__ psum,
                                               float* __restrict__ bsum,
                                               float* __restrict__ va) {
    int d = blockIdx.x * 256 + threadIdx.x;
    if (d >= DIM) return;
    float g = 0.f;
    for (int b = 0; b < BT; ++b) {
        float s = psum[(size_t)(b * 2) * DIM + d] + psum[(size_t)(b * 2 + 1) * DIM + d];
        bsum[b * DIM + d] = s;
        g += s;
    }
    va[d] = g * (1.f / NROWS);
}

// wave-per-row raw weights from f32 tg: w = 1/(db/P+eps) * 1/(da+eps)
__global__ __launch_bounds__(256) void k_wdots(const float* __restrict__ tg,
                                               const float* __restrict__ inv_tg,
                                               const float* __restrict__ bsum,
                                               const float* __restrict__ va,
                                               float* __restrict__ wraw) {
    int wave = threadIdx.x >> 6, lane = threadIdx.x & 63;
    int gw = blockIdx.x * 4 + wave;
#pragma unroll
    for (int rr = 0; rr < 4; ++rr) {
        int row = gw * 4 + rr;
        int b   = row >> 8;
        const float4* t4 = (const float4*)(tg + (size_t)row * DIM);
        const float4* b4 = (const float4*)(bsum + b * DIM);
        const float4* a4 = (const float4*)va;
        float db = 0.f, da = 0.f;
#pragma unroll
        for (int v = 0; v < 3; ++v) {
            float4 t = t4[lane + 64 * v];
            float4 x = b4[lane + 64 * v];
            float4 y = a4[lane + 64 * v];
            db += t.x * x.x + t.y * x.y + t.z * x.z + t.w * x.w;
            da += t.x * y.x + t.y * y.y + t.z * y.z + t.w * y.w;
        }
#pragma unroll
        for (int o = 32; o; o >>= 1) { db += __shfl_xor(db, o); da += __shfl_xor(da, o); }
        if (lane == 0) {
            float itg = inv_tg[row];
            db *= itg; da *= itg;
            wraw[row] = (1.f / (db * (1.f / PP) + EPSF)) * (1.f / (da + EPSF));
        }
    }
}

// normalize weights (deterministic per-block sum) + sim loss partial
__global__ __launch_bounds__(256) void k_wfinal(const float* __restrict__ wraw,
                                                const float* __restrict__ ploss,
                                                float* __restrict__ weights,
                                                float* __restrict__ accum) {
    __shared__ float red[256];
    int b = blockIdx.x, p = threadIdx.x, row = b * PP + p;
    float w = wraw[row];
    red[p] = w; __syncthreads();
    for (int s = 128; s; s >>= 1) { if (p < s) red[p] += red[p + s]; __syncthreads(); }
    float wn = w / (red[0] + EPSF);
    weights[row] = wn;
    __syncthreads();
    red[p] = wn * ploss[row]; __syncthreads();
    for (int s = 128; s; s >>= 1) { if (p < s) red[p] += red[p + s]; __syncthreads(); }
    if (p == 0) atomicAdd(&accum[0], red[0]);
}

// ---------------------------------------------------------------- kernel 4
// bf16 MFMA dual-gram (bf16 is safe here: only the gram DIFF uses it).
template<int PRE>
__global__ __launch_bounds__(256) void k_gram(const float* __restrict__ in,
                                              const float* __restrict__ tg,
                                              const unsigned short* __restrict__ in_n,
                                              const unsigned short* __restrict__ tg_n,
                                              const float* __restrict__ inv_in,
                                              const float* __restrict__ inv_tg,
                                              const float* __restrict__ weights,
                                              float* __restrict__ gacc) {
    __shared__ __align__(16) unsigned short LA0[128 * LP];
    __shared__ __align__(16) unsigned short LA1[128 * LP];
    __shared__ __align__(16) unsigned short LB0[128 * LP];
    __shared__ __align__(16) unsigned short LB1[128 * LP];
    __shared__ float red[256];

    const int wg  = blockIdx.x;
    const int xcd = wg & 7, j = wg >> 3;
    const int b   = xcd * 8 + j / 3;
    const int t3  = j % 3;
    const int pr  = (t3 == 2) ? 128 : 0;
    const int qc  = (t3 == 0) ? 0 : 128;
    const bool diag = (pr == qc);
    const float factor = diag ? 1.f : 2.f;

    const int tid  = threadIdx.x;
    const int lane = tid & 63;
    const int wave = tid >> 6;
    const int wr = (wave >> 1) * 64, wc = (wave & 1) * 64;
    const int bP = b * PP;

    const int strow = tid >> 2;
    const int skq   = tid & 3;
    const int sw    = (strow >> 3) & 3;

    const float* srcf[4] = { in, tg, in, tg };
    const unsigned short* srcn[4] = { in_n, tg_n, in_n, tg_n };
    unsigned short* ldst[4] = { LA0, LA1, LB0, LB1 };

    size_t g[4][2];
#pragma unroll
    for (int h = 0; h < 2; ++h) {
        g[0][h] = (size_t)(bP + pr + strow + h * 64) * DIM + skq * 8;
        g[1][h] = g[0][h];
        g[2][h] = (size_t)(bP + qc + strow + h * 64) * DIM + skq * 8;
        g[3][h] = g[2][h];
    }
    float scl[4][2];
    if constexpr (PRE == 0) {
#pragma unroll
        for (int h = 0; h < 2; ++h) {
            scl[0][h] = inv_in[bP + pr + strow + h * 64];
            scl[1][h] = inv_tg[bP + pr + strow + h * 64];
            scl[2][h] = inv_in[bP + qc + strow + h * 64];
            scl[3][h] = inv_tg[bP + qc + strow + h * 64];
        }
    }

    float4 pfa[4][2], pfb[4][2];
    us8    pn[4][2];

    auto STAGE_LOAD = [&](int k0) {
#pragma unroll
        for (int bi = 0; bi < 4; ++bi) {
            if (bi >= 2 && diag) continue;
#pragma unroll
            for (int h = 0; h < 2; ++h) {
                if constexpr (PRE != 0) {
                    pn[bi][h] = *(const us8*)(srcn[bi] + g[bi][h] + k0);
                } else {
                    pfa[bi][h] = *(const float4*)(srcf[bi] + g[bi][h] + k0);
                    pfb[bi][h] = *(const float4*)(srcf[bi] + g[bi][h] + k0 + 4);
                }
            }
        }
    };
    auto STAGE_WRITE = [&]() {
#pragma unroll
        for (int bi = 0; bi < 4; ++bi) {
            if (bi >= 2 && diag) continue;
#pragma unroll
            for (int h = 0; h < 2; ++h) {
                us8 v;
                if constexpr (PRE != 0) {
                    v = pn[bi][h];
                } else {
                    float s = scl[bi][h];
                    float4 x = pfa[bi][h], y = pfb[bi][h];
                    v[0] = f2bf(x.x * s); v[1] = f2bf(x.y * s);
                    v[2] = f2bf(x.z * s); v[3] = f2bf(x.w * s);
                    v[4] = f2bf(y.x * s); v[5] = f2bf(y.y * s);
                    v[6] = f2bf(y.z * s); v[7] = f2bf(y.w * s);
                }
                int row = strow + h * 64;
                *(us8*)&ldst[bi][row * LP + (skq ^ sw) * 8] = v;
            }
        }
    };

    const unsigned short* RB0 = diag ? LA0 : LB0;
    const unsigned short* RB1 = diag ? LA1 : LB1;

    f32x4 accI[4][4], accT[4][4];
#pragma unroll
    for (int m = 0; m < 4; ++m)
#pragma unroll
        for (int n = 0; n < 4; ++n) {
            f32x4 z = { 0.f, 0.f, 0.f, 0.f };
            accI[m][n] = z; accT[m][n] = z;
        }

    STAGE_LOAD(0);
    for (int ks = 0; ks < DIM / KC; ++ks) {
        __syncthreads();
        STAGE_WRITE();
        __syncthreads();
        if (ks + 1 < DIM / KC) STAGE_LOAD(KC * (ks + 1));

        bf16x8 aI[4], aT[4], bI[4], bT[4];
#pragma unroll
        for (int m = 0; m < 4; ++m) {
            int row = wr + m * 16 + (lane & 15);
            int off = row * LP + (((lane >> 4) ^ ((row >> 3) & 3))) * 8;
            aI[m] = *(const bf16x8*)&LA0[off];
            aT[m] = *(const bf16x8*)&LA1[off];
        }
#pragma unroll
        for (int n = 0; n < 4; ++n) {
            int row = wc + n * 16 + (lane & 15);
            int off = row * LP + (((lane >> 4) ^ ((row >> 3) & 3))) * 8;
            bI[n] = *(const bf16x8*)&RB0[off];
            bT[n] = *(const bf16x8*)&RB1[off];
        }
#pragma unroll
        for (int m = 0; m < 4; ++m)
#pragma unroll
            for (int n = 0; n < 4; ++n) {
                accI[m][n] = __builtin_amdgcn_mfma_f32_16x16x32_bf16(aI[m], bI[n], accI[m][n], 0, 0, 0);
                accT[m][n] = __builtin_amdgcn_mfma_f32_16x16x32_bf16(aT[m], bT[n], accT[m][n], 0, 0, 0);
            }
    }

    const int r4 = lane >> 4, cl = lane & 15;
    float wq[4], wp[4][4];
#pragma unroll
    for (int n = 0; n < 4; ++n) wq[n] = weights[bP + qc + wc + n * 16 + cl];
#pragma unroll
    for (int m = 0; m < 4; ++m)
#pragma unroll
        for (int r = 0; r < 4; ++r) wp[m][r] = weights[bP + pr + wr + m * 16 + r4 * 4 + r];
    float local = 0.f;
#pragma unroll
    for (int m = 0; m < 4; ++m)
#pragma unroll
        for (int n = 0; n < 4; ++n)
#pragma unroll
            for (int r = 0; r < 4; ++r) {
                float d = accI[m][n][r] - accT[m][n][r];
                local += wp[m][r] * wq[n] * d * d;
            }
    local *= factor;
    red[tid] = local; __syncthreads();
    for (int s = 128; s; s >>= 1) { if (tid < s) red[tid] += red[tid + s]; __syncthreads(); }
    if (tid == 0) atomicAdd(gacc, red[0]);
}

// ---------------------------------------------------------------- kernel 5
__global__ void k_final(const float* __restrict__ accum, float* __restrict__ out) {
    out[0] = (accum[0] + 10.f * accum[1]) * (1.f / BT);
}

// ---------------------------------------------------------------- launch
extern "C" void kernel_launch(void* const* d_in, const int* in_sizes, int n_in,
                              void* d_out, int out_size, void* d_ws, size_t ws_size,
                              hipStream_t stream) {
    (void)in_sizes; (void)n_in; (void)out_size;
    const float* in = (const float*)d_in[0];
    const float* tg = (const float*)d_in[1];

    const size_t bfBytes   = (size_t)NROWS * DIM * 2;
    const size_t floatsOff = 2 * bfBytes;
    // floats: inv_in, inv_tg, ploss, wraw, weights (5N) + psum(2*BT*DIM) + bsum(BT*DIM) + va(DIM) + accum(2)
    const size_t fCount    = 5 * (size_t)NROWS + 3 * (size_t)BT * DIM + DIM + 2;
    const size_t needed    = floatsOff + fCount * 4;
    const bool   pre       = ws_size >= needed;

    char* wsb = (char*)d_ws;
    unsigned short* in_n = nullptr;
    unsigned short* tg_n = nullptr;
    float* fbase;
    if (pre) {
        in_n  = (unsigned short*)wsb;
        tg_n  = (unsigned short*)(wsb + bfBytes);
        fbase = (float*)(wsb + floatsOff);
    } else {
        fbase = (float*)wsb;
    }
    float* inv_in  = fbase;
    float* inv_tg  = fbase + NROWS;
    float* ploss   = fbase + 2 * (size_t)NROWS;
    float* wraw    = fbase + 3 * (size_t)NROWS;
    float* weights = fbase + 4 * (size_t)NROWS;
    float* psum    = fbase + 5 * (size_t)NROWS;
    float* bsum    = psum + 2 * (size_t)BT * DIM;
    float* va      = bsum + (size_t)BT * DIM;
    float* accum   = va + DIM;   // [0]=sim, [1]=gram

    hipMemsetAsync(accum, 0, 2 * sizeof(float), stream);
    if (pre) {
        k_norms<1><<<NROWS / 4, 256, 0, stream>>>(in, tg, inv_in, inv_tg, ploss, in_n, tg_n);
    } else {
        k_norms<0><<<NROWS / 4, 256, 0, stream>>>(in, tg, inv_in, inv_tg, ploss, nullptr, nullptr);
    }
    k_bsum1<<<dim3(BT, 3, 2), 64, 0, stream>>>(tg, inv_tg, psum);
    k_bsum2<<<3, 256, 0, stream>>>(psum, bsum, va);
    k_wdots<<<NROWS / 16, 256, 0, stream>>>(tg, inv_tg, bsum, va, wraw);
    k_wfinal<<<BT, 256, 0, stream>>>(wraw, ploss, weights, accum);
    if (pre) {
        k_gram<1><<<192, 256, 0, stream>>>(in, tg, in_n, tg_n, inv_in, inv_tg, weights, accum + 1);
    } else {
        k_gram<0><<<192, 256, 0, stream>>>(in, tg, in_n, tg_n, inv_in, inv_tg, weights, accum + 1);
    }
    k_final<<<1, 1, 0, stream>>>(accum, (float*)d_out);
}